// Round 16
// baseline (29.308 us; speedup 1.0000x reference)
//
#include <hip/hip_runtime.h>
#include <hip/hip_bf16.h>
#include <math.h>

#define NODES 128
#define KMIX  8
#define NSAMP 4096
#define STOT  8192            // X and noise stacked
#define ZPAIR 8128            // 128*127/2
#define FDIM  256             // [cos | sin] feature dim

using bf16x8 = __attribute__((ext_vector_type(8))) short;
using f32x4  = __attribute__((ext_vector_type(4))) float;

// ---------------- ws layout (in float slots) ----------------
#define OF_F   ((size_t)0)                          // bf16 F[8192][256]
#define OF_M   (OF_F + (size_t)STOT * FDIM / 2)     // bf16 W[8][256][256]
#define OF_LP  (OF_M + (size_t)KMIX * FDIM * FDIM / 2)  // f32 lp32[8192][32]
#define OF_PT  (OF_LP + (size_t)32 * STOT)          // f32 [32] partials
#define OF_CT  (OF_PT + 32)                         // u32 [1] ticket counter

__device__ __forceinline__ float bf2f(short u) {
    union { unsigned u32; float f; } cv;
    cv.u32 = ((unsigned)(unsigned short)u) << 16;
    return cv.f;
}
__device__ __forceinline__ short f2bf(float f) {
    union { float f; unsigned u32; } cv; cv.f = f;
    unsigned r = cv.u32 + 0x7fff + ((cv.u32 >> 16) & 1);   // round-nearest-even
    return (short)(r >> 16);
}
__device__ __forceinline__ float softplusf(float x) {
    return fmaxf(x, 0.0f) + log1pf(expf(-fabsf(x)));
}

// ---------------------------------------------------------------------------
// prep (r15-verbatim): blocks [0,1024): sincos x4 vectorized; rest: build W
// W = [[S0/2, 0],[K1, S0/2]]
// ---------------------------------------------------------------------------
#define FEAT_BLOCKS4 (STOT * NODES / 4 / 256)       // 1024
#define WB_BLOCKS    (KMIX * FDIM * FDIM / 256)     // 2048

__global__ void prep_kernel(const float* __restrict__ X, const float* __restrict__ noise,
                            const float* __restrict__ theta,
                            short* __restrict__ F, short* __restrict__ W,
                            unsigned* __restrict__ ctr) {
    const int b = blockIdx.x, t = threadIdx.x;
    if (b == 0 && t == 0) *ctr = 0u;                // zero ticket (no memset node)
    if (b < FEAT_BLOCKS4) {
        int idx4 = (b * 256 + t) * 4;               // 0..1048572, multiple of 4
        int s = idx4 >> 7, i = idx4 & 127;          // i in {0,4,...,124}
        const float* src = (s < NSAMP) ? (X + idx4) : (noise + (idx4 - NSAMP * NODES));
        f32x4 v = *(const f32x4*)src;
        short cb[4], sb[4];
        #pragma unroll
        for (int q = 0; q < 4; q++) {
            float sv, cv;
            __sincosf(v[q], &sv, &cv);
            cb[q] = f2bf(cv); sb[q] = f2bf(sv);
        }
        *(short4*)&F[(size_t)s * FDIM + i]       = *(short4*)cb;
        *(short4*)&F[(size_t)s * FDIM + 128 + i] = *(short4*)sb;
    } else {
        int idx = (b - FEAT_BLOCKS4) * 256 + t;     // 0 .. KMIX*256*256-1
        int j = idx & 255, i = (idx >> 8) & 255, k = idx >> 16;
        int a = i & 127, bb = j & 127;
        int hi = i >> 7, hj = j >> 7;
        float val = 0.0f;
        if (a != bb) {
            int p = a < bb ? a : bb;
            int q = a < bb ? bb : a;
            int z = p * 127 - (p * (p - 1)) / 2 + (q - p - 1);
            if (hi == hj) {
                val = 0.5f * theta[(size_t)(k * 2 + 0) * ZPAIR + z];
            } else if (hi == 1 && hj == 0) {
                float t1 = theta[(size_t)(k * 2 + 1) * ZPAIR + z];
                val = (a < bb) ? t1 : -t1;
            }
        }
        W[idx] = f2bf(val);
    }
}

// ---------------------------------------------------------------------------
// combined GEMM, 8-wave blocks (2M x 4N): wave tile 64 samples x 32 i per half.
// acc 64 regs + afr 32 + bfr 16 fits the 128-reg bin -> 16 waves/CU (2 blocks).
// r9/r11-proven 6-step serial schedule; lp parts per k = 4 (one per wn).
// ---------------------------------------------------------------------------
__global__ __launch_bounds__(512, 4) void gemm_fused(
        const short* __restrict__ F, const short* __restrict__ M,
        float* __restrict__ lp32) {
    __shared__ short Ft[2][128 * 64];
    __shared__ short Mt[2][128 * 64];

    const int bid = blockIdx.x;
    const int k   = bid >> 6;          // 8 k x 64 s-tiles
    const int st  = bid & 63;
    const int sbase = st * 128;

    const int t = threadIdx.x;
    const int wid = t >> 6, lane = t & 63;
    const int wm = wid >> 2, wn = wid & 3;

    const short* Mk = M + (size_t)k * FDIM * FDIM;

    const int rg = lane >> 3;          // row within 8-row group (row&7 == rg)
    const int sc = (lane & 7) ^ rg;    // pre-swizzled source 16B-column

    f32x4 acc0[4][2] = {};             // P over i in [0,128), this wave's 32-col slice
    f32x4 acc1[4][2] = {};             // P over i in [128,256)

    auto stageF = [&](int buf, int c) {
        #pragma unroll
        for (int q = 0; q < 2; q++) {
            int g = wid * 2 + q;       // 16 groups x 8 rows = 128 rows
            const short* src = F + ((size_t)(sbase + g * 8 + rg)) * FDIM + c * 64 + sc * 8;
            __builtin_amdgcn_global_load_lds((const unsigned*)src,
                                             (unsigned*)&Ft[buf][g * 512], 16, 0, 0);
        }
    };
    auto stageW = [&](int buf, int ihrow, int c) {
        #pragma unroll
        for (int q = 0; q < 2; q++) {
            int g = wid * 2 + q;
            const short* src = Mk + ((size_t)(ihrow * 128 + g * 8 + rg)) * FDIM + c * 64 + sc * 8;
            __builtin_amdgcn_global_load_lds((const unsigned*)src,
                                             (unsigned*)&Mt[buf][g * 512], 16, 0, 0);
        }
    };

    const int rlow = lane & 15, kq = lane >> 4;

    bf16x8 afr[4][2], bfr[2][2];
    auto loadA = [&](int fbuf) {
        #pragma unroll
        for (int m = 0; m < 4; m++) {
            int row = wm * 64 + m * 16 + rlow;
            #pragma unroll
            for (int kk = 0; kk < 2; kk++) {
                int c16 = (kk * 4 + kq) ^ (row & 7);
                afr[m][kk] = *(const bf16x8*)&Ft[fbuf][row * 64 + c16 * 8];
            }
        }
    };
    auto loadB = [&](int mbuf) {
        #pragma unroll
        for (int n = 0; n < 2; n++) {
            int row = wn * 32 + n * 16 + rlow;
            #pragma unroll
            for (int kk = 0; kk < 2; kk++) {
                int c16 = (kk * 4 + kq) ^ (row & 7);
                bfr[n][kk] = *(const bf16x8*)&Mt[mbuf][row * 64 + c16 * 8];
            }
        }
    };
    auto mfma = [&](f32x4 (&acc)[4][2]) {
        __builtin_amdgcn_s_setprio(1);             // T5
        #pragma unroll
        for (int m = 0; m < 4; m++)
            #pragma unroll
            for (int n = 0; n < 2; n++)
                #pragma unroll
                for (int kk = 0; kk < 2; kk++)
                    acc[m][n] = __builtin_amdgcn_mfma_f32_16x16x32_bf16(
                        afr[m][kk], bfr[n][kk], acc[m][n], 0, 0, 0);
        __builtin_amdgcn_s_setprio(0);
    };
    auto compute = [&](int fbuf, int mbuf, f32x4 (&acc)[4][2]) {
        loadA(fbuf); loadB(mbuf); mfma(acc);
    };

    // steps: s0(ih0,c0,F0,M0) s1(ih1,c0,F0,M1) s2(ih0,c1,F1,M0)
    //        s3(ih1,c1,F1,M1) s4(ih1,c2,F0,M0) s5(ih1,c3,F1,M1)
    stageF(0, 0); stageW(0, 0, 0);
    stageW(1, 1, 0);
    __syncthreads();
    compute(0, 0, acc0);               // s0
    __syncthreads();
    stageF(1, 1); stageW(0, 0, 1);
    __syncthreads();
    compute(0, 1, acc1);               // s1
    __syncthreads();
    stageW(1, 1, 1);
    __syncthreads();
    compute(1, 0, acc0);               // s2
    __syncthreads();
    stageF(0, 2); stageW(0, 1, 2);
    __syncthreads();
    compute(1, 1, acc1);               // s3
    __syncthreads();
    stageF(1, 3); stageW(1, 1, 3);
    __syncthreads();
    compute(0, 0, acc1);               // s4
    __syncthreads();
    compute(1, 1, acc1);               // s5

    // ---- epilogue: psum[s] = sum over this wave's 32-i slice, both halves
    float psum[4][4];
    #pragma unroll
    for (int m = 0; m < 4; m++) {
        #pragma unroll
        for (int q = 0; q < 4; q++) {
            int srow = wm * 64 + m * 16 + kq * 4 + q;
            const short* fr0 = F + (size_t)(sbase + srow) * FDIM + wn * 32 + rlow;
            float p = 0.0f;
            #pragma unroll
            for (int n = 0; n < 2; n++)
                p += bf2f(fr0[n * 16]) * acc0[m][n][q];
            #pragma unroll
            for (int n = 0; n < 2; n++)
                p += bf2f(fr0[128 + n * 16]) * acc1[m][n][q];
            psum[m][q] = p;
        }
    }
    #pragma unroll
    for (int off = 1; off < 16; off <<= 1)
        #pragma unroll
        for (int m = 0; m < 4; m++)
            #pragma unroll
            for (int q = 0; q < 4; q++)
                psum[m][q] += __shfl_xor(psum[m][q], off, 64);

    if (rlow == 0) {
        #pragma unroll
        for (int m = 0; m < 4; m++)
            #pragma unroll
            for (int q = 0; q < 4; q++) {
                int srow = wm * 64 + m * 16 + kq * 4 + q;
                lp32[(size_t)(sbase + srow) * 32 + k * 4 + wn] = psum[m][q];
            }
    }
}

// ---------------------------------------------------------------------------
// reduce: coalesced 128B/thread lp32 reads; 4 parts per k summed in fixed
// order; ticket finalize (r11-proven).
// ---------------------------------------------------------------------------
__global__ void reduce_kernel(const float* __restrict__ lp32,
                              const float* __restrict__ logc,
                              float* __restrict__ partials,
                              unsigned* __restrict__ counter,
                              float* __restrict__ out) {
    const int t = threadIdx.x;
    const int s = blockIdx.x * 256 + t;

    const f32x4* base = (const f32x4*)&lp32[(size_t)s * 32];
    float v[KMIX];
    #pragma unroll
    for (int k = 0; k < KMIX; k++) {
        f32x4 r = base[k];
        v[k] = (r[0] + r[1]) + (r[2] + r[3]) + logc[k];
    }

    float mx = v[0];
    #pragma unroll
    for (int k = 1; k < KMIX; k++) mx = fmaxf(mx, v[k]);
    float sum = 0.0f;
    #pragma unroll
    for (int k = 0; k < KMIX; k++) sum += expf(v[k] - mx);
    const float lp = mx + logf(sum);

    // n == m -> term1 = -softplus(-lp_data), term2 = -softplus(lp_noise)
    const float term = (s < NSAMP) ? -softplusf(-lp) : -softplusf(lp);

    float bsum = term;
    #pragma unroll
    for (int off = 32; off; off >>= 1) bsum += __shfl_down(bsum, off);
    __shared__ float wsum[4];
    if ((t & 63) == 0) wsum[t >> 6] = bsum;
    __syncthreads();

    if (t == 0) {
        partials[blockIdx.x] = wsum[0] + wsum[1] + wsum[2] + wsum[3];
        __threadfence();                              // release partial
        unsigned old = atomicAdd(counter, 1u);        // device-scope ticket
        if (old == 31u) {                             // last block: finalize
            __threadfence();                          // acquire all partials
            float tot = 0.0f;
            #pragma unroll
            for (int b = 0; b < 32; b++) tot += partials[b];
            out[0] = tot * (1.0f / (float)NSAMP);
        }
    }
}

// ---------------------------------------------------------------------------
extern "C" void kernel_launch(void* const* d_in, const int* in_sizes, int n_in,
                              void* d_out, int out_size, void* d_ws, size_t ws_size,
                              hipStream_t stream) {
    (void)in_sizes; (void)n_in; (void)out_size; (void)ws_size;
    const float* X     = (const float*)d_in[0];
    const float* noise = (const float*)d_in[1];
    const float* theta = (const float*)d_in[2];
    const float* logc  = (const float*)d_in[3];
    float* out = (float*)d_out;
    float* ws  = (float*)d_ws;

    short*    Fb    = (short*)(ws + OF_F);
    short*    Wb    = (short*)(ws + OF_M);
    float*    lp32  = ws + OF_LP;
    float*    parts = ws + OF_PT;
    unsigned* ctr   = (unsigned*)(ws + OF_CT);

    prep_kernel<<<FEAT_BLOCKS4 + WB_BLOCKS, 256, 0, stream>>>(X, noise, theta, Fb, Wb, ctr);
    gemm_fused<<<KMIX * (STOT / 128), 512, 0, stream>>>(Fb, Wb, lp32);
    reduce_kernel<<<STOT / 256, 256, 0, stream>>>(lp32, logc, parts, ctr, out);
}

// Round 17
// 24.386 us; speedup vs baseline: 1.2019x; 1.2019x over previous
//
#include <hip/hip_runtime.h>
#include <hip/hip_bf16.h>
#include <math.h>

#define NODES 128
#define KMIX  8
#define NSAMP 4096
#define STOT  8192            // X and noise stacked
#define ZPAIR 8128            // 128*127/2
#define FDIM  256             // [cos | sin] feature dim

using bf16x8 = __attribute__((ext_vector_type(8))) short;
using f32x4  = __attribute__((ext_vector_type(4))) float;

// ---------------- ws layout (in float slots) ----------------
#define OF_F   ((size_t)0)                          // bf16 F[8192][256]
#define OF_M   (OF_F + (size_t)STOT * FDIM / 2)     // bf16 W[8][256][256]
#define OF_LP  (OF_M + (size_t)KMIX * FDIM * FDIM / 2)  // f32 lp16[8192][16]
#define OF_PT  (OF_LP + (size_t)16 * STOT)          // f32 [32] partials
#define OF_CT  (OF_PT + 32)                         // u32 [1] ticket counter

#define VMC(N) asm volatile("s_waitcnt vmcnt(" #N ")" ::: "memory")
#define LGKM0  asm volatile("s_waitcnt lgkmcnt(0)" ::: "memory")
#define SBAR   asm volatile("s_barrier" ::: "memory")

__device__ __forceinline__ float bf2f(short u) {
    union { unsigned u32; float f; } cv;
    cv.u32 = ((unsigned)(unsigned short)u) << 16;
    return cv.f;
}
__device__ __forceinline__ short f2bf(float f) {
    union { float f; unsigned u32; } cv; cv.f = f;
    unsigned r = cv.u32 + 0x7fff + ((cv.u32 >> 16) & 1);   // round-nearest-even
    return (short)(r >> 16);
}
__device__ __forceinline__ float softplusf(float x) {
    return fmaxf(x, 0.0f) + log1pf(expf(-fabsf(x)));
}

// ---------------------------------------------------------------------------
// prep: blocks [0,1024): sincos features, 4 elems/thread (float4 in, short4 out)
//       blocks [1024,3072): build W
// W = [[S0/2, 0],[K1, S0/2]]
// ---------------------------------------------------------------------------
#define FEAT_BLOCKS4 (STOT * NODES / 4 / 256)       // 1024
#define WB_BLOCKS    (KMIX * FDIM * FDIM / 256)     // 2048

__global__ void prep_kernel(const float* __restrict__ X, const float* __restrict__ noise,
                            const float* __restrict__ theta,
                            short* __restrict__ F, short* __restrict__ W,
                            unsigned* __restrict__ ctr) {
    const int b = blockIdx.x, t = threadIdx.x;
    if (b == 0 && t == 0) *ctr = 0u;                // zero ticket (no memset node)
    if (b < FEAT_BLOCKS4) {
        int idx4 = (b * 256 + t) * 4;               // 0..1048572, multiple of 4
        int s = idx4 >> 7, i = idx4 & 127;          // i in {0,4,...,124}
        const float* src = (s < NSAMP) ? (X + idx4) : (noise + (idx4 - NSAMP * NODES));
        f32x4 v = *(const f32x4*)src;               // 16B aligned
        short cb[4], sb[4];
        #pragma unroll
        for (int q = 0; q < 4; q++) {
            float sv, cv;
            __sincosf(v[q], &sv, &cv);
            cb[q] = f2bf(cv); sb[q] = f2bf(sv);
        }
        *(short4*)&F[(size_t)s * FDIM + i]       = *(short4*)cb;   // 8B aligned
        *(short4*)&F[(size_t)s * FDIM + 128 + i] = *(short4*)sb;
    } else {
        int idx = (b - FEAT_BLOCKS4) * 256 + t;     // 0 .. KMIX*256*256-1
        int j = idx & 255, i = (idx >> 8) & 255, k = idx >> 16;
        int a = i & 127, bb = j & 127;
        int hi = i >> 7, hj = j >> 7;
        float val = 0.0f;
        if (a != bb) {
            int p = a < bb ? a : bb;
            int q = a < bb ? bb : a;
            int z = p * 127 - (p * (p - 1)) / 2 + (q - p - 1);
            if (hi == hj) {
                val = 0.5f * theta[(size_t)(k * 2 + 0) * ZPAIR + z];
            } else if (hi == 1 && hj == 0) {
                float t1 = theta[(size_t)(k * 2 + 1) * ZPAIR + z];
                val = (a < bb) ? t1 : -t1;
            }
        }
        W[idx] = f2bf(val);
    }
}

// ---------------------------------------------------------------------------
// combined GEMM (counted-vmcnt pipeline) + T5 setprio around MFMA.
// lp output layout: lp16[s][k*2+wn] (contiguous 64B per sample for reduce).
// ---------------------------------------------------------------------------
__global__ __launch_bounds__(256, 2) void gemm_fused(
        const short* __restrict__ F, const short* __restrict__ M,
        float* __restrict__ lp16) {
    __shared__ short Ft[2][128 * 64];
    __shared__ short Mt[2][128 * 64];

    const int bid = blockIdx.x;
    const int k   = bid >> 6;          // 8 k x 64 s-tiles
    const int st  = bid & 63;
    const int sbase = st * 128;

    const int t = threadIdx.x;
    const int wid = t >> 6, lane = t & 63;
    const int wm = wid >> 1, wn = wid & 1;

    const short* Mk = M + (size_t)k * FDIM * FDIM;

    const int rg = lane >> 3;          // row within 8-row group (row&7 == rg)
    const int sc = (lane & 7) ^ rg;    // pre-swizzled source 16B-column

    f32x4 acc0[4][4] = {};             // P over i in [0,128)
    f32x4 acc1[4][4] = {};             // P over i in [128,256)

    auto stageF = [&](int buf, int c) {
        #pragma unroll
        for (int q = 0; q < 4; q++) {
            int g = wid * 4 + q;
            const short* src = F + ((size_t)(sbase + g * 8 + rg)) * FDIM + c * 64 + sc * 8;
            __builtin_amdgcn_global_load_lds((const unsigned*)src,
                                             (unsigned*)&Ft[buf][g * 512], 16, 0, 0);
        }
    };
    auto stageW = [&](int buf, int ihrow, int c) {
        #pragma unroll
        for (int q = 0; q < 4; q++) {
            int g = wid * 4 + q;
            const short* src = Mk + ((size_t)(ihrow * 128 + g * 8 + rg)) * FDIM + c * 64 + sc * 8;
            __builtin_amdgcn_global_load_lds((const unsigned*)src,
                                             (unsigned*)&Mt[buf][g * 512], 16, 0, 0);
        }
    };

    const int rlow = lane & 15, kq = lane >> 4;

    bf16x8 afr[4][2], bfr[4][2];
    auto loadA = [&](int fbuf) {
        #pragma unroll
        for (int m = 0; m < 4; m++) {
            int row = wm * 64 + m * 16 + rlow;
            #pragma unroll
            for (int kk = 0; kk < 2; kk++) {
                int c16 = (kk * 4 + kq) ^ (row & 7);
                afr[m][kk] = *(const bf16x8*)&Ft[fbuf][row * 64 + c16 * 8];
            }
        }
    };
    auto loadB = [&](int mbuf) {
        #pragma unroll
        for (int n = 0; n < 4; n++) {
            int row = wn * 64 + n * 16 + rlow;
            #pragma unroll
            for (int kk = 0; kk < 2; kk++) {
                int c16 = (kk * 4 + kq) ^ (row & 7);
                bfr[n][kk] = *(const bf16x8*)&Mt[mbuf][row * 64 + c16 * 8];
            }
        }
    };
    auto mfma = [&](f32x4 (&acc)[4][4]) {
        __builtin_amdgcn_s_setprio(1);             // T5: favor MFMA-issuing wave
        #pragma unroll
        for (int m = 0; m < 4; m++)
            #pragma unroll
            for (int n = 0; n < 4; n++)
                #pragma unroll
                for (int kk = 0; kk < 2; kk++)
                    acc[m][n] = __builtin_amdgcn_mfma_f32_16x16x32_bf16(
                        afr[m][kk], bfr[n][kk], acc[m][n], 0, 0, 0);
        __builtin_amdgcn_s_setprio(0);
    };

    // prologue: [F0c0(4), W00(4), W10(4)] -> outstanding 12
    stageF(0, 0); stageW(0, 0, 0); stageW(1, 1, 0);

    // step0 (ih0,c0: Ft0,Mt0) — needs oldest 8
    VMC(4); SBAR;
    loadA(0); loadB(0);
    LGKM0; SBAR;
    stageF(1, 1); stageW(0, 0, 1);     // step2 operands; Mt0 readers done
    mfma(acc0);
    // step1 (ih1,c0: Ft0,Mt1) — needs W10 (oldest 4 of 12)
    VMC(8); SBAR;
    loadA(0); loadB(1);
    LGKM0; SBAR;
    stageW(1, 1, 1);                   // step3 W; Mt1 readers done
    mfma(acc1);
    // step2 (ih0,c1: Ft1,Mt0) — needs F1c1+W0c1 (oldest 8 of 12)
    VMC(4); SBAR;
    loadA(1); loadB(0);
    LGKM0; SBAR;
    stageF(0, 2); stageW(0, 1, 2);     // step4 operands
    mfma(acc0);
    // step3 (ih1,c1: Ft1,Mt1) — needs W1c1 (oldest 4 of 12)
    VMC(8); SBAR;
    loadA(1); loadB(1);
    LGKM0; SBAR;
    stageF(1, 3); stageW(1, 1, 3);     // step5 operands
    mfma(acc1);
    // step4 (ih1,c2: Ft0,Mt0) — needs F0c2+W0c2 (oldest 8 of 16)
    VMC(8); SBAR;
    loadA(0); loadB(0);
    mfma(acc1);
    // step5 (ih1,c3: Ft1,Mt1) — last loads
    VMC(0); SBAR;
    loadA(1); loadB(1);
    mfma(acc1);

    // ---- epilogue: psum[s] = sum over BOTH i-halves of F[s,i]*P[s,i]
    float psum[4][4];
    #pragma unroll
    for (int m = 0; m < 4; m++) {
        #pragma unroll
        for (int q = 0; q < 4; q++) {
            int srow = wm * 64 + m * 16 + kq * 4 + q;
            const short* fr0 = F + (size_t)(sbase + srow) * FDIM + wn * 64 + rlow;
            float p = 0.0f;
            #pragma unroll
            for (int n = 0; n < 4; n++)
                p += bf2f(fr0[n * 16]) * acc0[m][n][q];
            #pragma unroll
            for (int n = 0; n < 4; n++)
                p += bf2f(fr0[128 + n * 16]) * acc1[m][n][q];
            psum[m][q] = p;
        }
    }
    #pragma unroll
    for (int off = 1; off < 16; off <<= 1)
        #pragma unroll
        for (int m = 0; m < 4; m++)
            #pragma unroll
            for (int q = 0; q < 4; q++)
                psum[m][q] += __shfl_xor(psum[m][q], off, 64);

    if (rlow == 0) {
        #pragma unroll
        for (int m = 0; m < 4; m++)
            #pragma unroll
            for (int q = 0; q < 4; q++) {
                int srow = wm * 64 + m * 16 + kq * 4 + q;
                lp16[(size_t)(sbase + srow) * 16 + k * 2 + wn] = psum[m][q];
            }
    }
}

// ---------------------------------------------------------------------------
// reduce: coalesced 64B/thread lp16 reads; ticket finalize.
// ---------------------------------------------------------------------------
__global__ void reduce_kernel(const float* __restrict__ lp16,
                              const float* __restrict__ logc,
                              float* __restrict__ partials,
                              unsigned* __restrict__ counter,
                              float* __restrict__ out) {
    const int t = threadIdx.x;
    const int s = blockIdx.x * 256 + t;

    const f32x4* base = (const f32x4*)&lp16[(size_t)s * 16];
    f32x4 r0 = base[0], r1 = base[1], r2 = base[2], r3 = base[3];

    float v[KMIX];
    v[0] = r0[0] + r0[1] + logc[0];
    v[1] = r0[2] + r0[3] + logc[1];
    v[2] = r1[0] + r1[1] + logc[2];
    v[3] = r1[2] + r1[3] + logc[3];
    v[4] = r2[0] + r2[1] + logc[4];
    v[5] = r2[2] + r2[3] + logc[5];
    v[6] = r3[0] + r3[1] + logc[6];
    v[7] = r3[2] + r3[3] + logc[7];

    float mx = v[0];
    #pragma unroll
    for (int k = 1; k < KMIX; k++) mx = fmaxf(mx, v[k]);
    float sum = 0.0f;
    #pragma unroll
    for (int k = 0; k < KMIX; k++) sum += expf(v[k] - mx);
    const float lp = mx + logf(sum);

    // n == m -> term1 = -softplus(-lp_data), term2 = -softplus(lp_noise)
    const float term = (s < NSAMP) ? -softplusf(-lp) : -softplusf(lp);

    float bsum = term;
    #pragma unroll
    for (int off = 32; off; off >>= 1) bsum += __shfl_down(bsum, off);
    __shared__ float wsum[4];
    if ((t & 63) == 0) wsum[t >> 6] = bsum;
    __syncthreads();

    if (t == 0) {
        partials[blockIdx.x] = wsum[0] + wsum[1] + wsum[2] + wsum[3];
        __threadfence();                              // release partial
        unsigned old = atomicAdd(counter, 1u);        // device-scope ticket
        if (old == 31u) {                             // last block: finalize
            __threadfence();                          // acquire all partials
            float tot = 0.0f;
            #pragma unroll
            for (int b = 0; b < 32; b++) tot += partials[b];
            out[0] = tot * (1.0f / (float)NSAMP);
        }
    }
}

// ---------------------------------------------------------------------------
extern "C" void kernel_launch(void* const* d_in, const int* in_sizes, int n_in,
                              void* d_out, int out_size, void* d_ws, size_t ws_size,
                              hipStream_t stream) {
    (void)in_sizes; (void)n_in; (void)out_size; (void)ws_size;
    const float* X     = (const float*)d_in[0];
    const float* noise = (const float*)d_in[1];
    const float* theta = (const float*)d_in[2];
    const float* logc  = (const float*)d_in[3];
    float* out = (float*)d_out;
    float* ws  = (float*)d_ws;

    short*    Fb    = (short*)(ws + OF_F);
    short*    Wb    = (short*)(ws + OF_M);
    float*    lp16  = ws + OF_LP;
    float*    parts = ws + OF_PT;
    unsigned* ctr   = (unsigned*)(ws + OF_CT);

    prep_kernel<<<FEAT_BLOCKS4 + WB_BLOCKS, 256, 0, stream>>>(X, noise, theta, Fb, Wb, ctr);
    gemm_fused<<<KMIX * (STOT / 128), 256, 0, stream>>>(Fb, Wb, lp16);
    reduce_kernel<<<STOT / 256, 256, 0, stream>>>(lp16, logc, parts, ctr, out);
}

// Round 18
// 24.187 us; speedup vs baseline: 1.2117x; 1.0082x over previous
//
#include <hip/hip_runtime.h>
#include <hip/hip_bf16.h>
#include <math.h>

#define NODES 128
#define KMIX  8
#define NSAMP 4096
#define STOT  8192            // X and noise stacked
#define ZPAIR 8128            // 128*127/2
#define FDIM  256             // [cos | sin] feature dim

using bf16x8 = __attribute__((ext_vector_type(8))) short;
using f32x4  = __attribute__((ext_vector_type(4))) float;

// ---------------- ws layout (in float slots) ----------------
#define OF_F   ((size_t)0)                          // bf16 F[8192][256]
#define OF_M   (OF_F + (size_t)STOT * FDIM / 2)     // bf16 W[8][256][256]
#define OF_LP  (OF_M + (size_t)KMIX * FDIM * FDIM / 2)  // f32 lp16[8192][16]
#define OF_PT  (OF_LP + (size_t)16 * STOT)          // f32 [32] partials
#define OF_CT  (OF_PT + 32)                         // u32 [1] ticket counter

#define VMC(N) asm volatile("s_waitcnt vmcnt(" #N ")" ::: "memory")
#define LGKM0  asm volatile("s_waitcnt lgkmcnt(0)" ::: "memory")
#define SBAR   asm volatile("s_barrier" ::: "memory")

__device__ __forceinline__ float bf2f(short u) {
    union { unsigned u32; float f; } cv;
    cv.u32 = ((unsigned)(unsigned short)u) << 16;
    return cv.f;
}
__device__ __forceinline__ short f2bf(float f) {
    union { float f; unsigned u32; } cv; cv.f = f;
    unsigned r = cv.u32 + 0x7fff + ((cv.u32 >> 16) & 1);   // round-nearest-even
    return (short)(r >> 16);
}
__device__ __forceinline__ float softplusf(float x) {
    return fmaxf(x, 0.0f) + log1pf(expf(-fabsf(x)));
}

// ---------------------------------------------------------------------------
// prep (r15-verbatim): blocks [0,1024): sincos x4 vectorized; rest: build W
// W = [[S0/2, 0],[K1, S0/2]]
// ---------------------------------------------------------------------------
#define FEAT_BLOCKS4 (STOT * NODES / 4 / 256)       // 1024
#define WB_BLOCKS    (KMIX * FDIM * FDIM / 256)     // 2048

__global__ void prep_kernel(const float* __restrict__ X, const float* __restrict__ noise,
                            const float* __restrict__ theta,
                            short* __restrict__ F, short* __restrict__ W,
                            unsigned* __restrict__ ctr) {
    const int b = blockIdx.x, t = threadIdx.x;
    if (b == 0 && t == 0) *ctr = 0u;                // zero ticket (no memset node)
    if (b < FEAT_BLOCKS4) {
        int idx4 = (b * 256 + t) * 4;               // 0..1048572, multiple of 4
        int s = idx4 >> 7, i = idx4 & 127;          // i in {0,4,...,124}
        const float* src = (s < NSAMP) ? (X + idx4) : (noise + (idx4 - NSAMP * NODES));
        f32x4 v = *(const f32x4*)src;               // 16B aligned
        short cb[4], sb[4];
        #pragma unroll
        for (int q = 0; q < 4; q++) {
            float sv, cv;
            __sincosf(v[q], &sv, &cv);
            cb[q] = f2bf(cv); sb[q] = f2bf(sv);
        }
        *(short4*)&F[(size_t)s * FDIM + i]       = *(short4*)cb;   // 8B aligned
        *(short4*)&F[(size_t)s * FDIM + 128 + i] = *(short4*)sb;
    } else {
        int idx = (b - FEAT_BLOCKS4) * 256 + t;     // 0 .. KMIX*256*256-1
        int j = idx & 255, i = (idx >> 8) & 255, k = idx >> 16;
        int a = i & 127, bb = j & 127;
        int hi = i >> 7, hj = j >> 7;
        float val = 0.0f;
        if (a != bb) {
            int p = a < bb ? a : bb;
            int q = a < bb ? bb : a;
            int z = p * 127 - (p * (p - 1)) / 2 + (q - p - 1);
            if (hi == hj) {
                val = 0.5f * theta[(size_t)(k * 2 + 0) * ZPAIR + z];
            } else if (hi == 1 && hj == 0) {
                float t1 = theta[(size_t)(k * 2 + 1) * ZPAIR + z];
                val = (a < bb) ? t1 : -t1;
            }
        }
        W[idx] = f2bf(val);
    }
}

// ---------------------------------------------------------------------------
// combined GEMM (r15-verbatim pipeline) + T1 XCD-aware block swizzle:
// XCD x (bid%8==x) owns st in [8x,8x+8) for all k -> per-XCD L2 working set
// 8 F-tiles (512KB) + W (1MB) = 1.5MB << 4MB L2 (vs ~5MB unswizzled).
// st = (bid%8)*8 + (bid/8)%8, k = bid/64  — bijective on 512 = 8*8*8.
// ---------------------------------------------------------------------------
__global__ __launch_bounds__(256, 2) void gemm_fused(
        const short* __restrict__ F, const short* __restrict__ M,
        float* __restrict__ lp16) {
    __shared__ short Ft[2][128 * 64];
    __shared__ short Mt[2][128 * 64];

    const int bid = blockIdx.x;
    const int k   = bid >> 6;                        // 0..7
    const int st  = (bid & 7) * 8 + ((bid >> 3) & 7);// T1 swizzle: 0..63
    const int sbase = st * 128;

    const int t = threadIdx.x;
    const int wid = t >> 6, lane = t & 63;
    const int wm = wid >> 1, wn = wid & 1;

    const short* Mk = M + (size_t)k * FDIM * FDIM;

    const int rg = lane >> 3;          // row within 8-row group (row&7 == rg)
    const int sc = (lane & 7) ^ rg;    // pre-swizzled source 16B-column

    f32x4 acc0[4][4] = {};             // P over i in [0,128)
    f32x4 acc1[4][4] = {};             // P over i in [128,256)

    auto stageF = [&](int buf, int c) {
        #pragma unroll
        for (int q = 0; q < 4; q++) {
            int g = wid * 4 + q;
            const short* src = F + ((size_t)(sbase + g * 8 + rg)) * FDIM + c * 64 + sc * 8;
            __builtin_amdgcn_global_load_lds((const unsigned*)src,
                                             (unsigned*)&Ft[buf][g * 512], 16, 0, 0);
        }
    };
    auto stageW = [&](int buf, int ihrow, int c) {
        #pragma unroll
        for (int q = 0; q < 4; q++) {
            int g = wid * 4 + q;
            const short* src = Mk + ((size_t)(ihrow * 128 + g * 8 + rg)) * FDIM + c * 64 + sc * 8;
            __builtin_amdgcn_global_load_lds((const unsigned*)src,
                                             (unsigned*)&Mt[buf][g * 512], 16, 0, 0);
        }
    };

    const int rlow = lane & 15, kq = lane >> 4;

    bf16x8 afr[4][2], bfr[4][2];
    auto loadA = [&](int fbuf) {
        #pragma unroll
        for (int m = 0; m < 4; m++) {
            int row = wm * 64 + m * 16 + rlow;
            #pragma unroll
            for (int kk = 0; kk < 2; kk++) {
                int c16 = (kk * 4 + kq) ^ (row & 7);
                afr[m][kk] = *(const bf16x8*)&Ft[fbuf][row * 64 + c16 * 8];
            }
        }
    };
    auto loadB = [&](int mbuf) {
        #pragma unroll
        for (int n = 0; n < 4; n++) {
            int row = wn * 64 + n * 16 + rlow;
            #pragma unroll
            for (int kk = 0; kk < 2; kk++) {
                int c16 = (kk * 4 + kq) ^ (row & 7);
                bfr[n][kk] = *(const bf16x8*)&Mt[mbuf][row * 64 + c16 * 8];
            }
        }
    };
    auto mfma = [&](f32x4 (&acc)[4][4]) {
        __builtin_amdgcn_s_setprio(1);             // T5: favor MFMA-issuing wave
        #pragma unroll
        for (int m = 0; m < 4; m++)
            #pragma unroll
            for (int n = 0; n < 4; n++)
                #pragma unroll
                for (int kk = 0; kk < 2; kk++)
                    acc[m][n] = __builtin_amdgcn_mfma_f32_16x16x32_bf16(
                        afr[m][kk], bfr[n][kk], acc[m][n], 0, 0, 0);
        __builtin_amdgcn_s_setprio(0);
    };

    // prologue: [F0c0(4), W00(4), W10(4)] -> outstanding 12
    stageF(0, 0); stageW(0, 0, 0); stageW(1, 1, 0);

    // step0 (ih0,c0: Ft0,Mt0) — needs oldest 8
    VMC(4); SBAR;
    loadA(0); loadB(0);
    LGKM0; SBAR;
    stageF(1, 1); stageW(0, 0, 1);     // step2 operands; Mt0 readers done
    mfma(acc0);
    // step1 (ih1,c0: Ft0,Mt1) — needs W10 (oldest 4 of 12)
    VMC(8); SBAR;
    loadA(0); loadB(1);
    LGKM0; SBAR;
    stageW(1, 1, 1);                   // step3 W; Mt1 readers done
    mfma(acc1);
    // step2 (ih0,c1: Ft1,Mt0) — needs F1c1+W0c1 (oldest 8 of 12)
    VMC(4); SBAR;
    loadA(1); loadB(0);
    LGKM0; SBAR;
    stageF(0, 2); stageW(0, 1, 2);     // step4 operands
    mfma(acc0);
    // step3 (ih1,c1: Ft1,Mt1) — needs W1c1 (oldest 4 of 12)
    VMC(8); SBAR;
    loadA(1); loadB(1);
    LGKM0; SBAR;
    stageF(1, 3); stageW(1, 1, 3);     // step5 operands
    mfma(acc1);
    // step4 (ih1,c2: Ft0,Mt0) — needs F0c2+W0c2 (oldest 8 of 16)
    VMC(8); SBAR;
    loadA(0); loadB(0);
    mfma(acc1);
    // step5 (ih1,c3: Ft1,Mt1) — last loads
    VMC(0); SBAR;
    loadA(1); loadB(1);
    mfma(acc1);

    // ---- epilogue: psum[s] = sum over BOTH i-halves of F[s,i]*P[s,i]
    float psum[4][4];
    #pragma unroll
    for (int m = 0; m < 4; m++) {
        #pragma unroll
        for (int q = 0; q < 4; q++) {
            int srow = wm * 64 + m * 16 + kq * 4 + q;
            const short* fr0 = F + (size_t)(sbase + srow) * FDIM + wn * 64 + rlow;
            float p = 0.0f;
            #pragma unroll
            for (int n = 0; n < 4; n++)
                p += bf2f(fr0[n * 16]) * acc0[m][n][q];
            #pragma unroll
            for (int n = 0; n < 4; n++)
                p += bf2f(fr0[128 + n * 16]) * acc1[m][n][q];
            psum[m][q] = p;
        }
    }
    #pragma unroll
    for (int off = 1; off < 16; off <<= 1)
        #pragma unroll
        for (int m = 0; m < 4; m++)
            #pragma unroll
            for (int q = 0; q < 4; q++)
                psum[m][q] += __shfl_xor(psum[m][q], off, 64);

    if (rlow == 0) {
        #pragma unroll
        for (int m = 0; m < 4; m++)
            #pragma unroll
            for (int q = 0; q < 4; q++) {
                int srow = wm * 64 + m * 16 + kq * 4 + q;
                lp16[(size_t)(sbase + srow) * 16 + k * 2 + wn] = psum[m][q];
            }
    }
}

// ---------------------------------------------------------------------------
// reduce (r15-verbatim): coalesced 64B/thread lp16 reads; ticket finalize.
// ---------------------------------------------------------------------------
__global__ void reduce_kernel(const float* __restrict__ lp16,
                              const float* __restrict__ logc,
                              float* __restrict__ partials,
                              unsigned* __restrict__ counter,
                              float* __restrict__ out) {
    const int t = threadIdx.x;
    const int s = blockIdx.x * 256 + t;

    const f32x4* base = (const f32x4*)&lp16[(size_t)s * 16];
    f32x4 r0 = base[0], r1 = base[1], r2 = base[2], r3 = base[3];

    float v[KMIX];
    v[0] = r0[0] + r0[1] + logc[0];
    v[1] = r0[2] + r0[3] + logc[1];
    v[2] = r1[0] + r1[1] + logc[2];
    v[3] = r1[2] + r1[3] + logc[3];
    v[4] = r2[0] + r2[1] + logc[4];
    v[5] = r2[2] + r2[3] + logc[5];
    v[6] = r3[0] + r3[1] + logc[6];
    v[7] = r3[2] + r3[3] + logc[7];

    float mx = v[0];
    #pragma unroll
    for (int k = 1; k < KMIX; k++) mx = fmaxf(mx, v[k]);
    float sum = 0.0f;
    #pragma unroll
    for (int k = 0; k < KMIX; k++) sum += expf(v[k] - mx);
    const float lp = mx + logf(sum);

    // n == m -> term1 = -softplus(-lp_data), term2 = -softplus(lp_noise)
    const float term = (s < NSAMP) ? -softplusf(-lp) : -softplusf(lp);

    float bsum = term;
    #pragma unroll
    for (int off = 32; off; off >>= 1) bsum += __shfl_down(bsum, off);
    __shared__ float wsum[4];
    if ((t & 63) == 0) wsum[t >> 6] = bsum;
    __syncthreads();

    if (t == 0) {
        partials[blockIdx.x] = wsum[0] + wsum[1] + wsum[2] + wsum[3];
        __threadfence();                              // release partial
        unsigned old = atomicAdd(counter, 1u);        // device-scope ticket
        if (old == 31u) {                             // last block: finalize
            __threadfence();                          // acquire all partials
            float tot = 0.0f;
            #pragma unroll
            for (int b = 0; b < 32; b++) tot += partials[b];
            out[0] = tot * (1.0f / (float)NSAMP);
        }
    }
}

// ---------------------------------------------------------------------------
extern "C" void kernel_launch(void* const* d_in, const int* in_sizes, int n_in,
                              void* d_out, int out_size, void* d_ws, size_t ws_size,
                              hipStream_t stream) {
    (void)in_sizes; (void)n_in; (void)out_size; (void)ws_size;
    const float* X     = (const float*)d_in[0];
    const float* noise = (const float*)d_in[1];
    const float* theta = (const float*)d_in[2];
    const float* logc  = (const float*)d_in[3];
    float* out = (float*)d_out;
    float* ws  = (float*)d_ws;

    short*    Fb    = (short*)(ws + OF_F);
    short*    Wb    = (short*)(ws + OF_M);
    float*    lp16  = ws + OF_LP;
    float*    parts = ws + OF_PT;
    unsigned* ctr   = (unsigned*)(ws + OF_CT);

    prep_kernel<<<FEAT_BLOCKS4 + WB_BLOCKS, 256, 0, stream>>>(X, noise, theta, Fb, Wb, ctr);
    gemm_fused<<<KMIX * (STOT / 128), 256, 0, stream>>>(Fb, Wb, lp16);
    reduce_kernel<<<STOT / 256, 256, 0, stream>>>(lp16, logc, parts, ctr, out);
}